// Round 1
// 279.720 us; speedup vs baseline: 1.0093x; 1.0093x over previous
//
#include <hip/hip_runtime.h>
#include <hip/hip_bf16.h>
#include <stdint.h>

// Problem constants (fixed shape): B=16, L=65536, H=64, K=64
#define LCOUNT 65536
#define LOUT   65473   // L - (H-1)
#define KF     64
#define HH     64
#define TL     1024    // output positions per block
#define ROW    1096    // rep row stride in shorts; 1096 % 64 == 8 -> row bases stagger banks by 4

typedef __attribute__((ext_vector_type(8))) short  short8;   // 8 bf16 (4 VGPRs)
typedef __attribute__((ext_vector_type(4))) float  float4v;  // 4 fp32
typedef __attribute__((ext_vector_type(2))) float  float2v;  // 2 fp32

__device__ __forceinline__ unsigned short f2bf(float f) {
    union { float f; uint32_t u; } c; c.f = f;
    uint32_t u = c.u;
    u += 0x7FFFu + ((u >> 16) & 1u);   // round-to-nearest-even
    return (unsigned short)(u >> 16);
}

__global__ __launch_bounds__(256, 4)
void hankel_kernel(const float* __restrict__ x,
                   const float* __restrict__ W,
                   const float* __restrict__ bias,
                   float* __restrict__ out)
{
    // LDS: 4352 + 17536 + 8192 + 256 + 256 = 30592 B  -> >=4 blocks/CU
    __shared__ __align__(16) float          xs_f[TL + 64];
    __shared__ __align__(16) unsigned short rep[8 * ROW];   // rep[s][i] = bf16(x[block_lo + i + s])
    __shared__ __align__(16) float          muinv_s[2 * TL]; // interleaved {mu, inv}
    __shared__ float wsum_s[KF];
    __shared__ float bias_s[KF];

    const int tid  = threadIdx.x;
    const int lane = tid & 63;
    const int wv   = tid >> 6;
    const int m    = lane & 15;   // A-row (filter sub-idx) AND C/D col (position)
    const int quad = lane >> 4;

    const int tile     = blockIdx.x;
    const int bb       = blockIdx.y;
    const int block_lo = tile * TL;

    // ---- Phase A: stage x tile (float4 loads): fp32 for stats + packed bf16 row 0 ----
    {
        const float4v* xrow4 = (const float4v*)(x + (size_t)bb * LCOUNT);
        const int base4 = block_lo >> 2;           // block_lo % 4 == 0
        const int nf4   = (TL + 64) / 4;           // 272
        for (int i4 = tid; i4 < nf4; i4 += 256) {
            int g4 = base4 + i4;
            if (g4 > LCOUNT / 4 - 1) g4 = LCOUNT / 4 - 1;  // tail clamp; masked at store
            float4v v = xrow4[g4];
            *(float4v*)(xs_f + 4 * i4) = v;
            uint32_t plo = (uint32_t)f2bf(v[0]) | ((uint32_t)f2bf(v[1]) << 16);
            uint32_t phi = (uint32_t)f2bf(v[2]) | ((uint32_t)f2bf(v[3]) << 16);
            *(uint2*)(rep + 4 * i4) = make_uint2(plo, phi);   // row 0 (shift 0)
        }
    }

    // ---- Wsum[k] and bias -> LDS (threads 0..63; W is 16KB L1/L2-hot) ----
    if (tid < KF) {
        const float4v* wr = (const float4v*)(W + tid * HH);
        float s = 0.f;
        #pragma unroll
        for (int i = 0; i < HH / 4; ++i) {
            float4v w = wr[i];
            s += w[0] + w[1] + w[2] + w[3];
        }
        wsum_s[tid] = s;
        bias_s[tid] = bias[tid];
    }

    // ---- A fragments (W): afrag[t][ki] -> A[m=lane&15][h=quad*8+j+32*ki], filter k=t*16+m ----
    short8 afrag[4][2];
    #pragma unroll
    for (int t = 0; t < 4; ++t) {
        const int k = t * 16 + m;
        #pragma unroll
        for (int ki = 0; ki < 2; ++ki) {
            const float4v* wp = (const float4v*)(W + k * HH + quad * 8 + ki * 32);
            float4v w0 = wp[0];
            float4v w1 = wp[1];
            short8 f;
            f[0] = (short)f2bf(w0[0]); f[1] = (short)f2bf(w0[1]);
            f[2] = (short)f2bf(w0[2]); f[3] = (short)f2bf(w0[3]);
            f[4] = (short)f2bf(w1[0]); f[5] = (short)f2bf(w1[1]);
            f[6] = (short)f2bf(w1[2]); f[7] = (short)f2bf(w1[3]);
            afrag[t][ki] = f;
        }
    }

    __syncthreads();

    // ---- Phase B1: window stats: thread owns 4 consecutive positions p0 = 4*tid .. +3 ----
    {
        const int p0 = 4 * tid;
        const float4v* xv = (const float4v*)(xs_f + p0);   // 16B aligned
        float s1 = 0.f, s2 = 0.f;
        float4v v0 = xv[0];
        float4v v16 = xv[16];
        #pragma unroll
        for (int i = 0; i < 16; ++i) {
            float4v v = xv[i];
            s1 += v[0] + v[1] + v[2] + v[3];
            s2 += v[0] * v[0] + v[1] * v[1] + v[2] * v[2] + v[3] * v[3];
        }
        float mu4[4], inv4[4];
        #pragma unroll
        for (int i = 0; i < 4; ++i) {
            if (i > 0) {
                float xo = v0[i - 1], xn = v16[i - 1];   // slide window by 1
                s1 += xn - xo;
                s2 += xn * xn - xo * xo;
            }
            float mu  = s1 * (1.f / 64.f);
            float var = (s2 - 64.f * mu * mu) * (1.f / 63.f);
            var = var < 0.f ? 0.f : var;
            mu4[i]  = mu;
            inv4[i] = 1.f / (sqrtf(var) + 1e-6f);
        }
        float4v lo4, hi4;
        lo4[0] = mu4[0]; lo4[1] = inv4[0]; lo4[2] = mu4[1]; lo4[3] = inv4[1];
        hi4[0] = mu4[2]; hi4[1] = inv4[2]; hi4[2] = mu4[3]; hi4[3] = inv4[3];
        *(float4v*)(muinv_s + 8 * tid)     = lo4;   // byte 32*tid -> 16B aligned
        *(float4v*)(muinv_s + 8 * tid + 4) = hi4;
    }

    // ---- Phase B2: build shifted bf16 rows 1..7 from row 0 (aligned b128 reads later) ----
    // rep[s][8c .. 8c+7] = row0[8c+s .. 8c+s+7];  135 chunks x 7 shifts = 945 tasks (s==0 skipped)
    for (int tt = tid; tt < 1080; tt += 256) {
        const int s = tt & 7;
        const int c = tt >> 3;          // 0..134
        if (s) {
            const int i0 = 8 * c + s;   // max 1079+7=1086 < 1088 staged
            short8 w;
            #pragma unroll
            for (int j = 0; j < 8; ++j) w[j] = (short)rep[i0 + j];
            *(short8*)(rep + s * ROW + 8 * c) = w;   // byte s*2192 + 16c -> 16B aligned
        }
    }
    __syncthreads();

    // ---- Phase C: MFMA phase: 16 position-groups per wave ----
    // B[k=quad*8+j][n=m] = x[p0 + m + quad*8 + j (+32*ki)]
    //   = rep[m&7][ p0 + (m&8) + quad*8 + j (+32*ki) ]  -- base ≡ 0 mod 8 shorts -> 16B aligned
    const unsigned short* myrow = rep + (m & 7) * ROW + (m & 8) + quad * 8;

    for (int g = wv; g < TL / 16; g += 4) {
        const int p0 = g * 16;

        short8 b0 = *(const short8*)(myrow + p0);        // 1x ds_read_b128, conflict-free
        short8 b1 = *(const short8*)(myrow + p0 + 32);   // 1x ds_read_b128, conflict-free

        // per-lane position stats (C/D col = m): single b64
        float2v mi = *(const float2v*)(muinv_s + 2 * (p0 + m));
        const float muv  = mi[0];
        const float invv = mi[1];
        const int   lo   = block_lo + p0 + m;

        float4v acc[4];
        #pragma unroll
        for (int t = 0; t < 4; ++t) acc[t] = (float4v){0.f, 0.f, 0.f, 0.f};

        #pragma unroll
        for (int t = 0; t < 4; ++t) {
            acc[t] = __builtin_amdgcn_mfma_f32_16x16x32_bf16(afrag[t][0], b0, acc[t], 0, 0, 0);
            acc[t] = __builtin_amdgcn_mfma_f32_16x16x32_bf16(afrag[t][1], b1, acc[t], 0, 0, 0);
        }

        // ---- epilogue: fold layernorm + bias + relu; dwordx4 stores ----
        if (lo < LOUT) {
            float* op = out + ((size_t)bb * LOUT + lo) * KF + quad * 4;
            #pragma unroll
            for (int t = 0; t < 4; ++t) {
                // loop-invariant broadcast reads; LICM hoists to regs if pressure allows
                float4v ws = *(const float4v*)(wsum_s + t * 16 + quad * 4);
                float4v bs = *(const float4v*)(bias_s + t * 16 + quad * 4);
                float4v v;
                #pragma unroll
                for (int r = 0; r < 4; ++r) {
                    float vv = (acc[t][r] - muv * ws[r]) * invv + bs[r];
                    v[r] = vv > 0.f ? vv : 0.f;
                }
                *(float4v*)(op + t * 16) = v;
            }
        }
    }

    // ---- output 1: warmup scalar = 63 ----
    if (tile == 0 && bb == 0 && tid == 0) {
        out[(size_t)16 * LOUT * KF] = 63.0f;
    }
}

extern "C" void kernel_launch(void* const* d_in, const int* in_sizes, int n_in,
                              void* d_out, int out_size, void* d_ws, size_t ws_size,
                              hipStream_t stream) {
    const float* x = (const float*)d_in[0];   // (16, 65536) fp32
    const float* W = (const float*)d_in[1];   // (64, 64) fp32
    const float* b = (const float*)d_in[2];   // (64,) fp32
    float* out = (float*)d_out;               // 16*65473*64 fp32 + 1 (warmup)

    dim3 grid((LOUT + TL - 1) / TL, 16);      // 64 tiles x 16 batches
    hankel_kernel<<<grid, 256, 0, stream>>>(x, W, b, out);
}

// Round 2
// 272.493 us; speedup vs baseline: 1.0361x; 1.0265x over previous
//
#include <hip/hip_runtime.h>
#include <hip/hip_bf16.h>
#include <stdint.h>

// Problem constants (fixed shape): B=16, L=65536, H=64, K=64
#define LCOUNT 65536
#define LOUT   65473   // L - (H-1)
#define KF     64
#define HH     64
#define TL     1024    // output positions per block
#define ROW    1096    // rep row stride in shorts; 1096 % 64 == 8 -> row bases stagger banks by 4
#define BSTRIDE 36     // bounce row stride in floats; (36 % 8 == 4) -> (m+q)%8 bank groups, even

typedef __attribute__((ext_vector_type(8))) short  short8;   // 8 bf16 (4 VGPRs)
typedef __attribute__((ext_vector_type(4))) float  float4v;  // 4 fp32
typedef __attribute__((ext_vector_type(2))) float  float2v;  // 2 fp32

__device__ __forceinline__ unsigned short f2bf(float f) {
    union { float f; uint32_t u; } c; c.f = f;
    uint32_t u = c.u;
    u += 0x7FFFu + ((u >> 16) & 1u);   // round-to-nearest-even
    return (unsigned short)(u >> 16);
}

__global__ __launch_bounds__(256, 4)
void hankel_kernel(const float* __restrict__ x,
                   const float* __restrict__ W,
                   const float* __restrict__ bias,
                   float* __restrict__ out)
{
    // LDS: 4352 + 17536 + 8192 + 256 + 256 + 9216 = 39808 B -> 4 blocks/CU (<= 40960)
    __shared__ __align__(16) float          xs_f[TL + 64];
    __shared__ __align__(16) unsigned short rep[8 * ROW];     // rep[s][i] = bf16(x[block_lo + i + s])
    __shared__ __align__(16) float          muinv_s[2 * TL];  // interleaved {mu, inv}
    __shared__ float wsum_s[KF];
    __shared__ float bias_s[KF];
    __shared__ __align__(16) float          bounce[4][16][BSTRIDE];  // per-wave store-coalescing buffer

    const int tid  = threadIdx.x;
    const int lane = tid & 63;
    const int wv   = tid >> 6;
    const int m    = lane & 15;   // A-row (filter sub-idx) AND C/D col (position)
    const int quad = lane >> 4;

    const int tile     = blockIdx.x;
    const int bb       = blockIdx.y;
    const int block_lo = tile * TL;

    // ---- Phase A: stage x tile (float4 loads): fp32 for stats + packed bf16 row 0 ----
    {
        const float4v* xrow4 = (const float4v*)(x + (size_t)bb * LCOUNT);
        const int base4 = block_lo >> 2;           // block_lo % 4 == 0
        const int nf4   = (TL + 64) / 4;           // 272
        for (int i4 = tid; i4 < nf4; i4 += 256) {
            int g4 = base4 + i4;
            if (g4 > LCOUNT / 4 - 1) g4 = LCOUNT / 4 - 1;  // tail clamp; masked at store
            float4v v = xrow4[g4];
            *(float4v*)(xs_f + 4 * i4) = v;
            uint32_t plo = (uint32_t)f2bf(v[0]) | ((uint32_t)f2bf(v[1]) << 16);
            uint32_t phi = (uint32_t)f2bf(v[2]) | ((uint32_t)f2bf(v[3]) << 16);
            *(uint2*)(rep + 4 * i4) = make_uint2(plo, phi);   // row 0 (shift 0)
        }
    }

    // ---- Wsum[k] and bias -> LDS (threads 0..63; W is 16KB L1/L2-hot) ----
    if (tid < KF) {
        const float4v* wr = (const float4v*)(W + tid * HH);
        float s = 0.f;
        #pragma unroll
        for (int i = 0; i < HH / 4; ++i) {
            float4v w = wr[i];
            s += w[0] + w[1] + w[2] + w[3];
        }
        wsum_s[tid] = s;
        bias_s[tid] = bias[tid];
    }

    // ---- A fragments (W): afrag[t][ki] -> A[m=lane&15][h=quad*8+j+32*ki], filter k=t*16+m ----
    short8 afrag[4][2];
    #pragma unroll
    for (int t = 0; t < 4; ++t) {
        const int k = t * 16 + m;
        #pragma unroll
        for (int ki = 0; ki < 2; ++ki) {
            const float4v* wp = (const float4v*)(W + k * HH + quad * 8 + ki * 32);
            float4v w0 = wp[0];
            float4v w1 = wp[1];
            short8 f;
            f[0] = (short)f2bf(w0[0]); f[1] = (short)f2bf(w0[1]);
            f[2] = (short)f2bf(w0[2]); f[3] = (short)f2bf(w0[3]);
            f[4] = (short)f2bf(w1[0]); f[5] = (short)f2bf(w1[1]);
            f[6] = (short)f2bf(w1[2]); f[7] = (short)f2bf(w1[3]);
            afrag[t][ki] = f;
        }
    }

    __syncthreads();

    // ---- Phase B1: window stats: thread owns 4 consecutive positions p0 = 4*tid .. +3 ----
    {
        const int p0 = 4 * tid;
        const float4v* xv = (const float4v*)(xs_f + p0);   // 16B aligned
        float s1 = 0.f, s2 = 0.f;
        float4v v0 = xv[0];
        float4v v16 = xv[16];
        #pragma unroll
        for (int i = 0; i < 16; ++i) {
            float4v v = xv[i];
            s1 += v[0] + v[1] + v[2] + v[3];
            s2 += v[0] * v[0] + v[1] * v[1] + v[2] * v[2] + v[3] * v[3];
        }
        float mu4[4], inv4[4];
        #pragma unroll
        for (int i = 0; i < 4; ++i) {
            if (i > 0) {
                float xo = v0[i - 1], xn = v16[i - 1];   // slide window by 1
                s1 += xn - xo;
                s2 += xn * xn - xo * xo;
            }
            float mu  = s1 * (1.f / 64.f);
            float var = (s2 - 64.f * mu * mu) * (1.f / 63.f);
            var = var < 0.f ? 0.f : var;
            mu4[i]  = mu;
            inv4[i] = 1.f / (sqrtf(var) + 1e-6f);
        }
        float4v lo4, hi4;
        lo4[0] = mu4[0]; lo4[1] = inv4[0]; lo4[2] = mu4[1]; lo4[3] = inv4[1];
        hi4[0] = mu4[2]; hi4[1] = inv4[2]; hi4[2] = mu4[3]; hi4[3] = inv4[3];
        *(float4v*)(muinv_s + 8 * tid)     = lo4;   // byte 32*tid -> 16B aligned
        *(float4v*)(muinv_s + 8 * tid + 4) = hi4;
    }

    // ---- Phase B2: build shifted bf16 rows 1..7 from row 0 (aligned b128 reads later) ----
    for (int tt = tid; tt < 1080; tt += 256) {
        const int s = tt & 7;
        const int c = tt >> 3;          // 0..134
        if (s) {
            const int i0 = 8 * c + s;   // max 1079+7=1086 < 1088 staged
            short8 w;
            #pragma unroll
            for (int j = 0; j < 8; ++j) w[j] = (short)rep[i0 + j];
            *(short8*)(rep + s * ROW + 8 * c) = w;   // byte s*2192 + 16c -> 16B aligned
        }
    }
    __syncthreads();

    // ---- Phase C: MFMA + coalesced-store phase ----
    // B[k=quad*8+j][n=m] = rep[m&7][ p0 + (m&8) + quad*8 + j (+32*ki) ]  -- 16B aligned
    const unsigned short* myrow = rep + (m & 7) * ROW + (m & 8) + quad * 8;
    float* const bw = &bounce[wv][0][0];
    float* const outb = out + (size_t)bb * LOUT * KF;

    // hoisted loop-invariant broadcasts (g-invariant)
    float4v ws4[4], bs4[4];
    #pragma unroll
    for (int t = 0; t < 4; ++t) {
        ws4[t] = *(const float4v*)(wsum_s + t * 16 + quad * 4);
        bs4[t] = *(const float4v*)(bias_s + t * 16 + quad * 4);
    }

    for (int g = wv; g < TL / 16; g += 4) {
        const int p0 = g * 16;

        short8 b0 = *(const short8*)(myrow + p0);        // ds_read_b128, conflict-free
        short8 b1 = *(const short8*)(myrow + p0 + 32);   // ds_read_b128, conflict-free

        float2v mi = *(const float2v*)(muinv_s + 2 * (p0 + m));
        const float muv  = mi[0];
        const float invv = mi[1];

        float4v acc[4];
        #pragma unroll
        for (int t = 0; t < 4; ++t) acc[t] = (float4v){0.f, 0.f, 0.f, 0.f};

        #pragma unroll
        for (int t = 0; t < 4; ++t) {
            acc[t] = __builtin_amdgcn_mfma_f32_16x16x32_bf16(afrag[t][0], b0, acc[t], 0, 0, 0);
            acc[t] = __builtin_amdgcn_mfma_f32_16x16x32_bf16(afrag[t][1], b1, acc[t], 0, 0, 0);
        }

        // ---- epilogue: fold layernorm + bias + relu, then LDS-bounce to full-line stores ----
        // Two k-halves (h): each bounce 16 pos x 32 k (2 KB), then store as aligned 128B-line
        // chunks, 1KB contiguous per instruction (fill-kernel shape).
        #pragma unroll
        for (int h = 0; h < 2; ++h) {
            #pragma unroll
            for (int e = 0; e < 2; ++e) {
                const int t = 2 * h + e;
                float4v v;
                #pragma unroll
                for (int r = 0; r < 4; ++r) {
                    float vv = (acc[t][r] - muv * ws4[t][r]) * invv + bs4[t][r];
                    v[r] = vv > 0.f ? vv : 0.f;
                }
                // write: bank group (m+quad)%8 -> even, conflict-free b128
                *(float4v*)(bw + m * BSTRIDE + e * 16 + quad * 4) = v;
            }
            // cross-lane visibility within the wave (LDS is in-order per wave; this
            // stops compiler reordering and drains the writes)
            asm volatile("s_waitcnt lgkmcnt(0)" ::: "memory");
            #pragma unroll
            for (int s = 0; s < 2; ++s) {
                const int pos_in = 8 * s + (lane >> 3);            // 0..15
                const int kh     = 4 * (lane & 7);                 // 0..28
                // read: bank group ((lane>>3)+(lane&7))%8 -> even, conflict-free b128
                float4v v = *(const float4v*)(bw + pos_in * BSTRIDE + kh);
                const int pos = block_lo + p0 + pos_in;
                if (pos < LOUT) {
                    // 1KB contiguous per instr; each pos chunk = aligned full 128B line
                    *(float4v*)(outb + (size_t)pos * KF + 32 * h + kh) = v;
                }
            }
            asm volatile("" ::: "memory");   // keep next half's writes after these reads
        }
    }

    // ---- output 1: warmup scalar = 63 ----
    if (tile == 0 && bb == 0 && tid == 0) {
        out[(size_t)16 * LOUT * KF] = 63.0f;
    }
}

extern "C" void kernel_launch(void* const* d_in, const int* in_sizes, int n_in,
                              void* d_out, int out_size, void* d_ws, size_t ws_size,
                              hipStream_t stream) {
    const float* x = (const float*)d_in[0];   // (16, 65536) fp32
    const float* W = (const float*)d_in[1];   // (64, 64) fp32
    const float* b = (const float*)d_in[2];   // (64,) fp32
    float* out = (float*)d_out;               // 16*65473*64 fp32 + 1 (warmup)

    dim3 grid((LOUT + TL - 1) / TL, 16);      // 64 tiles x 16 batches
    hankel_kernel<<<grid, 256, 0, stream>>>(x, W, b, out);
}